// Round 5
// baseline (211.683 us; speedup 1.0000x reference)
//
#include <hip/hip_runtime.h>
#include <hip/hip_fp16.h>
#include <cstdint>

#define DM    1472
#define NH    6
#define DKV   64
#define INNER 384
#define BATCH 4
#define SEQ   2048
#define LOG2E 1.4426950408889634f

typedef __attribute__((ext_vector_type(8))) _Float16 half8;
typedef __attribute__((ext_vector_type(4))) _Float16 half4;
typedef __attribute__((ext_vector_type(4))) float f32x4;

__device__ __forceinline__ int swz64(int row, int b)  { return b ^ (((row >> 1) & 3) << 4); }
__device__ __forceinline__ int swz128(int row, int b) { return b ^ ((row & 7) << 4); }

__device__ __forceinline__ void gload16(const void* g, const void* l) {
  __builtin_amdgcn_global_load_lds((const __attribute__((address_space(1))) void*)g,
                                   (__attribute__((address_space(3))) void*)l, 16, 0, 0);
}

// ---------------- prep: weights fp32 -> fp16 transposed ----------------
__global__ void prep_weights(const float* __restrict__ WQ, const float* __restrict__ WK,
                             const float* __restrict__ WV, const float* __restrict__ WO,
                             _Float16* __restrict__ WqT, _Float16* __restrict__ WkT,
                             _Float16* __restrict__ WvT, _Float16* __restrict__ WoT) {
  int idx = blockIdx.x * blockDim.x + threadIdx.x;
  const int per = DM * INNER;
  if (idx >= 4 * per) return;
  int which = idx / per;
  int i = idx - which * per;
  if (which < 3) {
    const float* W = which == 0 ? WQ : (which == 1 ? WK : WV);
    _Float16* T = which == 0 ? WqT : (which == 1 ? WkT : WvT);
    int k = i / INNER, n = i - (i / INNER) * INNER;
    T[(size_t)n * DM + k] = (_Float16)W[i];   // [INNER][DM] = W^T
  } else {
    int k = i / DM, n = i - (i / DM) * DM;
    WoT[(size_t)n * INNER + k] = (_Float16)WO[i];  // [DM][INNER] = WO^T
  }
}

// ---------------- prep: shift-replicated bias table biasS[h][c][4104] ----------------
__global__ void prep_bias(const float* __restrict__ rel_bias, float* __restrict__ biasS) {
  int idx = blockIdx.x * blockDim.x + threadIdx.x;
  const int TOT = NH * 4 * 4104;
  if (idx >= TOT) return;
  int h = idx / (4 * 4104);
  int rem = idx - h * 4 * 4104;
  int cc = rem / 4104;
  int i = rem - cc * 4104;
  int j = i + cc; if (j > 4094) j = 4094;
  int d = j - 2047;                 // relative position k - q
  int ret = d > 0 ? 16 : 0;
  int a = d < 0 ? -d : d;
  int bucket;
  if (a < 8) bucket = ret + a;
  else {
    int large;
    if      (a >= 91) large = 15;
    else if (a >= 64) large = 14;
    else if (a >= 46) large = 13;
    else if (a >= 32) large = 12;
    else if (a >= 23) large = 11;
    else if (a >= 16) large = 10;
    else if (a >= 12) large = 9;
    else              large = 8;
    bucket = ret + large;
  }
  biasS[idx] = rel_bias[bucket * NH + h] * LOG2E;
}

// ---------------- projection GEMM, m97-structure ----------------
__global__ __launch_bounds__(256) void proj_gemm(
    const float* __restrict__ Xq, const float* __restrict__ Xkv,
    const _Float16* __restrict__ WqT, const _Float16* __restrict__ WkvT,
    _Float16* __restrict__ Qo, _Float16* __restrict__ Ko, _Float16* __restrict__ Vto) {
  const int bm = blockIdx.x, by = blockIdx.y;
  const bool isQ = by < 3;
  const float* __restrict__ X = isQ ? Xq : Xkv;
  const _Float16* __restrict__ WT = isQ ? (WqT + (size_t)by * 128 * DM)
                                        : (WkvT + (size_t)(by - 3) * 128 * DM);

  __shared__ alignas(16) float    As[2][128 * 32];
  __shared__ alignas(16) _Float16 Bs[2][128 * 32];

  const int tid = threadIdx.x;
  const int lane = tid & 63, wave = tid >> 6;
  const int wm = wave >> 1, wn = wave & 1;
  const int l15 = lane & 15, lg = lane >> 4;

  f32x4 acc[4][4] = {};

  const int aoff = 4 * ((lane & 7) ^ (lane >> 3));
  const float* asrc[4];
#pragma unroll
  for (int c = 0; c < 4; ++c)
    asrc[c] = X + (size_t)(bm * 128 + (wave * 4 + c) * 8 + (lane >> 3)) * DM + aoff;
  const int boff = 8 * ((lane & 3) ^ ((lane >> 3) & 3));
  const _Float16* bsrc[2];
#pragma unroll
  for (int c = 0; c < 2; ++c)
    bsrc[c] = WT + (size_t)((wave * 2 + c) * 16 + (lane >> 2)) * DM + boff;

  const int NT = DM / 32;   // 46

#pragma unroll
  for (int c = 0; c < 4; ++c)
    gload16(asrc[c], (const char*)&As[0][0] + (wave * 4 + c) * 1024);
#pragma unroll
  for (int c = 0; c < 2; ++c)
    gload16(bsrc[c], (const char*)&Bs[0][0] + (wave * 2 + c) * 1024);
  __syncthreads();

  for (int t = 0; t < NT; ++t) {
    if (t + 1 < NT) {
      const int nb = (t + 1) & 1;
      const int kf = (t + 1) * 32;
#pragma unroll
      for (int c = 0; c < 4; ++c)
        gload16(asrc[c] + kf, (const char*)&As[nb][0] + (wave * 4 + c) * 1024);
#pragma unroll
      for (int c = 0; c < 2; ++c)
        gload16(bsrc[c] + kf, (const char*)&Bs[nb][0] + (wave * 2 + c) * 1024);
    }

    const char* Ab = (const char*)&As[t & 1][0];
    const char* Bb = (const char*)&Bs[t & 1][0];
    half8 af[4], bf[4];
#pragma unroll
    for (int m = 0; m < 4; ++m) {
      int r = wm * 64 + m * 16 + l15;
      int s = (r & 7) << 4;
      f32x4 x0 = *(const f32x4*)(Ab + r * 128 + ((lg * 32) ^ s));
      f32x4 x1 = *(const f32x4*)(Ab + r * 128 + ((lg * 32 + 16) ^ s));
      half8 h;
#pragma unroll
      for (int j = 0; j < 4; ++j) { h[j] = (_Float16)x0[j]; h[4 + j] = (_Float16)x1[j]; }
      af[m] = h;
    }
#pragma unroll
    for (int n = 0; n < 4; ++n) {
      int r = wn * 64 + n * 16 + l15;
      bf[n] = *(const half8*)(Bb + r * 64 + ((lg * 16) ^ (((r >> 1) & 3) << 4)));
    }

    __builtin_amdgcn_s_setprio(1);
#pragma unroll
    for (int m = 0; m < 4; ++m)
#pragma unroll
      for (int n = 0; n < 4; ++n)
        acc[m][n] = __builtin_amdgcn_mfma_f32_16x16x32_f16(af[m], bf[n], acc[m][n], 0, 0, 0);
    __builtin_amdgcn_s_setprio(0);

    __syncthreads();
  }

#pragma unroll
  for (int m = 0; m < 4; ++m)
#pragma unroll
    for (int n = 0; n < 4; ++n)
#pragma unroll
      for (int r = 0; r < 4; ++r) {
        int gm = bm * 128 + wm * 64 + m * 16 + lg * 4 + r;
        int gnl = wn * 64 + n * 16 + l15;
        int b = gm >> 11, s = gm & 2047;
        float av = acc[m][n][r];
        if (isQ) {
          int gn = by * 128 + gnl;
          int h = gn >> 6, dd = gn & 63;
          Qo[((size_t)(b * NH + h) * SEQ + s) * DKV + dd] = (_Float16)(av * LOG2E);
        } else {
          int gn = (by - 3) * 128 + gnl;
          if (gn < INNER) {
            int h = gn >> 6, dd = gn & 63;
            Ko[((size_t)(b * NH + h) * SEQ + s) * DKV + dd] = (_Float16)av;
          } else {
            int gnv = gn - INNER;
            int h = gnv >> 6, dd = gnv & 63;
            Vto[((size_t)(b * NH + h) * DKV + dd) * SEQ + s] = (_Float16)av;
          }
        }
      }
}

// ---------------- flash attention v3: KVBLK=128, single-buffer + reg prefetch ----------------
__global__ __launch_bounds__(256, 3) void attn_kernel(
    const _Float16* __restrict__ Q, const _Float16* __restrict__ K, const _Float16* __restrict__ Vt,
    const float* __restrict__ biasS, const float* __restrict__ mask, _Float16* __restrict__ AO) {
  const int bid = blockIdx.x;
  const int g = (bid & 7) * 96 + (bid >> 3);
  const int bh = g >> 5, qb = g & 31;
  const int b = bh / NH, h = bh - b * NH;
  const int q0 = qb * 64;
  const int tid = threadIdx.x, lane = tid & 63, wave = tid >> 6;
  const int l15 = lane & 15, lg = lane >> 4;

  __shared__ alignas(16) _Float16 Ks[128 * 64];     // 16 KB, row k (128B rows)
  __shared__ alignas(16) _Float16 Vs[64 * 128];     // 16 KB, row d (256B rows)
  __shared__ alignas(16) _Float16 Ps[4][16 * 128];  // 16 KB, per-wave, row q (256B rows)

  const size_t bhS = (size_t)bh * SEQ;
  const int qq = q0 + wave * 16 + l15;

  const _Float16* Qbase = Q + (bhS + q0 + wave * 16) * DKV;
  half8 qf0 = *(const half8*)(Qbase + (size_t)l15 * DKV + lg * 8);
  half8 qf1 = *(const half8*)(Qbase + (size_t)l15 * DKV + 32 + lg * 8);

  const float* maskrow = mask + (size_t)b * SEQ * SEQ + (size_t)qq * SEQ + lg * 4;
  const int c = (3 - l15) & 3;
  const float* bbase = biasS + (size_t)(h * 4 + c) * 4104 + (lg * 4 - qq + 2047 - c);

  float m_r = -1e30f, l_r = 0.f;
  f32x4 oacc[4] = {};

  // staging geometry
  const int krow = tid >> 1, kc0 = (tid & 1) * 4;   // K: 128 rows x 8 chunks
  const int vrow = tid >> 2, vc0 = (tid & 3) * 4;   // V: 64 rows x 16 chunks
  const _Float16* Vg = Vt + ((size_t)bh * DKV + vrow) * SEQ;
  char* KsB = (char*)Ks;
  char* VsB = (char*)Vs;
  char* PsB = (char*)&Ps[wave][0];

  // prologue: stage tile 0
  {
    half8 kn[4], vn[4];
#pragma unroll
    for (int j = 0; j < 4; ++j) {
      kn[j] = *(const half8*)(K + (bhS + krow) * DKV + (kc0 + j) * 8);
      vn[j] = *(const half8*)(Vg + (vc0 + j) * 8);
    }
#pragma unroll
    for (int j = 0; j < 4; ++j) {
      *(half8*)(KsB + krow * 128 + (((kc0 + j) ^ (krow & 7)) << 4)) = kn[j];
      *(half8*)(VsB + vrow * 256 + (((vc0 + j) ^ (vrow & 15)) << 4)) = vn[j];
    }
  }
  __syncthreads();

  const int NTI = SEQ / 128;  // 16
  for (int t = 0; t < NTI; ++t) {
    const int kt = t * 128;

    // issue K/V prefetch for t+1 (consumed after the post-PV barrier)
    half8 kn[4], vn[4];
    if (t + 1 < NTI) {
      const int knx = kt + 128;
#pragma unroll
      for (int j = 0; j < 4; ++j) {
        kn[j] = *(const half8*)(K + (bhS + knx + krow) * DKV + (kc0 + j) * 8);
        vn[j] = *(const half8*)(Vg + knx + (vc0 + j) * 8);
      }
    }
    // issue mask loads for this tile (hidden under QK^T)
    f32x4 mcur[8];
#pragma unroll
    for (int nf = 0; nf < 8; ++nf)
      mcur[nf] = *(const f32x4*)(maskrow + kt + nf * 16);

    // S^T = K Q^T
    f32x4 sacc[8] = {};
    __builtin_amdgcn_s_setprio(1);
#pragma unroll
    for (int nf = 0; nf < 8; ++nf) {
      int kr = nf * 16 + l15;
      const char* rb = KsB + kr * 128;
      int sw = kr & 7;
      half8 kf0 = *(const half8*)(rb + ((lg ^ sw) << 4));
      half8 kf1 = *(const half8*)(rb + (((4 + lg) ^ sw) << 4));
      sacc[nf] = __builtin_amdgcn_mfma_f32_16x16x32_f16(kf0, qf0, sacc[nf], 0, 0, 0);
      sacc[nf] = __builtin_amdgcn_mfma_f32_16x16x32_f16(kf1, qf1, sacc[nf], 0, 0, 0);
    }
    __builtin_amdgcn_s_setprio(0);

    // logits = S + bias + mask*log2e  (bias prescaled; tree-max)
    float sv[8][4];
    float fm[8];
#pragma unroll
    for (int nf = 0; nf < 8; ++nf) {
      f32x4 bv = *(const f32x4*)(bbase + kt + nf * 16);
#pragma unroll
      for (int r = 0; r < 4; ++r)
        sv[nf][r] = sacc[nf][r] + bv[r] + mcur[nf][r] * LOG2E;
      fm[nf] = fmaxf(fmaxf(sv[nf][0], sv[nf][1]), fmaxf(sv[nf][2], sv[nf][3]));
    }
    float mx = fmaxf(fmaxf(fmaxf(fm[0], fm[1]), fmaxf(fm[2], fm[3])),
                     fmaxf(fmaxf(fm[4], fm[5]), fmaxf(fm[6], fm[7])));
    mx = fmaxf(mx, __shfl_xor(mx, 16));
    mx = fmaxf(mx, __shfl_xor(mx, 32));

    // defer-max: rescale only when the running max actually grows past THR=8
    if (!__all(mx <= m_r + 8.0f)) {
      float mnew = fmaxf(m_r, mx);
      float sc_ = __builtin_amdgcn_exp2f(m_r - mnew);
      m_r = mnew;
      l_r *= sc_;
      f32x4 scv;
#pragma unroll
      for (int r = 0; r < 4; ++r) scv[r] = __shfl(sc_, lg * 4 + r);
#pragma unroll
      for (int df = 0; df < 4; ++df) oacc[df] *= scv;
    }

    float rs = 0.f;
#pragma unroll
    for (int nf = 0; nf < 8; ++nf) {
      half4 ph;
#pragma unroll
      for (int r = 0; r < 4; ++r) {
        float p = __builtin_amdgcn_exp2f(sv[nf][r] - m_r);
        rs += p;
        ph[r] = (_Float16)p;
      }
      *(half4*)(PsB + l15 * 256 + ((((nf * 2 + (lg >> 1)) ^ l15) << 4) + (lg & 1) * 8)) = ph;
    }
    rs += __shfl_xor(rs, 16);
    rs += __shfl_xor(rs, 32);
    l_r += rs;

    // O += P V
    __builtin_amdgcn_s_setprio(1);
#pragma unroll
    for (int ks = 0; ks < 4; ++ks) {
      half8 pa = *(const half8*)(PsB + l15 * 256 + (((ks * 4 + lg) ^ l15) << 4));
#pragma unroll
      for (int df = 0; df < 4; ++df) {
        int vr = df * 16 + l15;
        half8 vb = *(const half8*)(VsB + vr * 256 + (((ks * 4 + lg) ^ (vr & 15)) << 4));
        oacc[df] = __builtin_amdgcn_mfma_f32_16x16x32_f16(pa, vb, oacc[df], 0, 0, 0);
      }
    }
    __builtin_amdgcn_s_setprio(0);

    __syncthreads();   // all waves done reading Ks/Vs of tile t
    if (t + 1 < NTI) {
#pragma unroll
      for (int j = 0; j < 4; ++j) {
        *(half8*)(KsB + krow * 128 + (((kc0 + j) ^ (krow & 7)) << 4)) = kn[j];
        *(half8*)(VsB + vrow * 256 + (((vc0 + j) ^ (vrow & 15)) << 4)) = vn[j];
      }
    }
    __syncthreads();   // tile t+1 staged
  }

  // epilogue
  f32x4 lv;
#pragma unroll
  for (int r = 0; r < 4; ++r) lv[r] = __shfl(l_r, lg * 4 + r);
#pragma unroll
  for (int df = 0; df < 4; ++df) {
    int dd = df * 16 + l15;
#pragma unroll
    for (int r = 0; r < 4; ++r) {
      int qrow = q0 + wave * 16 + lg * 4 + r;
      AO[((size_t)(b * SEQ + qrow)) * INNER + h * DKV + dd] = (_Float16)(oacc[df][r] / lv[r]);
    }
  }
}

// ---------------- output GEMM: AO[8192,384]f16 @ WO -> out fp32, double-buffered ----------------
__global__ __launch_bounds__(256) void out_gemm(
    const _Float16* __restrict__ A, const _Float16* __restrict__ BT, float* __restrict__ C) {
  __shared__ alignas(16) _Float16 As[2][128 * 32];
  __shared__ alignas(16) _Float16 Bs[2][64 * 32];

  const int tid = threadIdx.x, lane = tid & 63, wave = tid >> 6;
  const int wm = wave >> 1, wn = wave & 1;
  const int bm = blockIdx.x, bn = blockIdx.y;
  const int l15 = lane & 15, lg = lane >> 4;

  f32x4 acc[4][2] = {};
  const int arow = tid >> 1, aseg = tid & 1;
  const int brow = tid >> 2, bchunk = tid & 3;
  const _Float16* asrc = A + (size_t)(bm * 128 + arow) * INNER + aseg * 16;
  const _Float16* bsrc = BT + (size_t)(bn * 64 + brow) * INNER + bchunk * 8;

  const int NT = INNER / 32;  // 12

  {
    half8 a0 = *(const half8*)(asrc);
    half8 a1 = *(const half8*)(asrc + 8);
    half8 b0 = *(const half8*)(bsrc);
    char* AsW = (char*)&As[0][0];
    char* BsW = (char*)&Bs[0][0];
    *(half8*)(AsW + arow * 64 + swz64(arow, aseg * 32)) = a0;
    *(half8*)(AsW + arow * 64 + swz64(arow, aseg * 32 + 16)) = a1;
    *(half8*)(BsW + brow * 64 + swz64(brow, bchunk * 16)) = b0;
  }

  for (int t = 0; t < NT; ++t) {
    __syncthreads();
    const bool pre = (t + 1 < NT);
    half8 na0, na1, nb0;
    if (pre) {
      const int kn = (t + 1) * 32;
      na0 = *(const half8*)(asrc + kn);
      na1 = *(const half8*)(asrc + kn + 8);
      nb0 = *(const half8*)(bsrc + kn);
    }

    const char* AsB = (const char*)&As[t & 1][0];
    const char* BsB = (const char*)&Bs[t & 1][0];
    half8 af[4], bf[2];
#pragma unroll
    for (int m = 0; m < 4; ++m) {
      int r = wm * 64 + m * 16 + l15;
      af[m] = *(const half8*)(AsB + r * 64 + swz64(r, lg * 16));
    }
#pragma unroll
    for (int n = 0; n < 2; ++n) {
      int r = wn * 32 + n * 16 + l15;
      bf[n] = *(const half8*)(BsB + r * 64 + swz64(r, lg * 16));
    }
    __builtin_amdgcn_s_setprio(1);
#pragma unroll
    for (int m = 0; m < 4; ++m)
#pragma unroll
      for (int n = 0; n < 2; ++n)
        acc[m][n] = __builtin_amdgcn_mfma_f32_16x16x32_f16(af[m], bf[n], acc[m][n], 0, 0, 0);
    __builtin_amdgcn_s_setprio(0);

    if (pre) {
      char* AsW = (char*)&As[(t + 1) & 1][0];
      char* BsW = (char*)&Bs[(t + 1) & 1][0];
      *(half8*)(AsW + arow * 64 + swz64(arow, aseg * 32)) = na0;
      *(half8*)(AsW + arow * 64 + swz64(arow, aseg * 32 + 16)) = na1;
      *(half8*)(BsW + brow * 64 + swz64(brow, bchunk * 16)) = nb0;
    }
  }

#pragma unroll
  for (int m = 0; m < 4; ++m)
#pragma unroll
    for (int n = 0; n < 2; ++n)
#pragma unroll
      for (int r = 0; r < 4; ++r) {
        int gm = bm * 128 + wm * 64 + m * 16 + lg * 4 + r;
        int gn = bn * 64 + wn * 32 + n * 16 + l15;
        C[(size_t)gm * DM + gn] = acc[m][n][r];
      }
}

// ---------------- launch ----------------
extern "C" void kernel_launch(void* const* d_in, const int* in_sizes, int n_in,
                              void* d_out, int out_size, void* d_ws, size_t ws_size,
                              hipStream_t stream) {
  const float* kv   = (const float*)d_in[0];
  const float* qs   = (const float*)d_in[1];
  const float* mask = (const float*)d_in[2];
  const float* WQ   = (const float*)d_in[3];
  const float* WK   = (const float*)d_in[4];
  const float* WV   = (const float*)d_in[5];
  const float* WO   = (const float*)d_in[6];
  const float* rb   = (const float*)d_in[7];
  float* out = (float*)d_out;
  char* ws = (char*)d_ws;

  const size_t WT_BYTES  = (size_t)INNER * DM * 2;
  const size_t QKV_BYTES = (size_t)BATCH * NH * SEQ * DKV * 2;
  _Float16* WqT = (_Float16*)(ws);
  _Float16* WkT = (_Float16*)(ws + WT_BYTES);      // WkT + WvT contiguous => [768][DM]
  _Float16* WvT = (_Float16*)(ws + 2 * WT_BYTES);
  _Float16* WoT = (_Float16*)(ws + 3 * WT_BYTES);
  _Float16* Qh  = (_Float16*)(ws + 4 * WT_BYTES);
  _Float16* Kh  = (_Float16*)(ws + 4 * WT_BYTES + QKV_BYTES);
  _Float16* Vth = (_Float16*)(ws + 4 * WT_BYTES + 2 * QKV_BYTES);
  _Float16* AO  = (_Float16*)(ws + 4 * WT_BYTES + 3 * QKV_BYTES);
  float* biasS  = (float*)(ws + 4 * WT_BYTES + 4 * QKV_BYTES);

  hipLaunchKernelGGL(prep_weights, dim3((4 * DM * INNER + 255) / 256), dim3(256), 0, stream,
                     WQ, WK, WV, WO, WqT, WkT, WvT, WoT);
  hipLaunchKernelGGL(prep_bias, dim3((NH * 4 * 4104 + 255) / 256), dim3(256), 0, stream, rb, biasS);
  hipLaunchKernelGGL(proj_gemm, dim3(64, 9), dim3(256), 0, stream,
                     qs, kv, WqT, WkT, Qh, Kh, Vth);
  hipLaunchKernelGGL(attn_kernel, dim3(768), dim3(256), 0, stream,
                     Qh, Kh, Vth, biasS, mask, AO);
  hipLaunchKernelGGL(out_gemm, dim3(64, 23), dim3(256), 0, stream, AO, WoT, out);
}

// Round 6
// 194.592 us; speedup vs baseline: 1.0878x; 1.0878x over previous
//
#include <hip/hip_runtime.h>
#include <hip/hip_fp16.h>
#include <cstdint>

#define DM    1472
#define NH    6
#define DKV   64
#define INNER 384
#define BATCH 4
#define SEQ   2048
#define LOG2E 1.4426950408889634f

typedef __attribute__((ext_vector_type(8))) _Float16 half8;
typedef __attribute__((ext_vector_type(4))) _Float16 half4;
typedef __attribute__((ext_vector_type(4))) float f32x4;

__device__ __forceinline__ int swz64(int row, int b)  { return b ^ (((row >> 1) & 3) << 4); }
__device__ __forceinline__ int swz128(int row, int b) { return b ^ ((row & 7) << 4); }

__device__ __forceinline__ void gload16(const void* g, const void* l) {
  __builtin_amdgcn_global_load_lds((const __attribute__((address_space(1))) void*)g,
                                   (__attribute__((address_space(3))) void*)l, 16, 0, 0);
}

// ---------------- prep: weights fp32 -> fp16 transposed ----------------
__global__ void prep_weights(const float* __restrict__ WQ, const float* __restrict__ WK,
                             const float* __restrict__ WV, const float* __restrict__ WO,
                             _Float16* __restrict__ WqT, _Float16* __restrict__ WkT,
                             _Float16* __restrict__ WvT, _Float16* __restrict__ WoT) {
  int idx = blockIdx.x * blockDim.x + threadIdx.x;
  const int per = DM * INNER;
  if (idx >= 4 * per) return;
  int which = idx / per;
  int i = idx - which * per;
  if (which < 3) {
    const float* W = which == 0 ? WQ : (which == 1 ? WK : WV);
    _Float16* T = which == 0 ? WqT : (which == 1 ? WkT : WvT);
    int k = i / INNER, n = i - (i / INNER) * INNER;
    T[(size_t)n * DM + k] = (_Float16)W[i];   // [INNER][DM] = W^T
  } else {
    int k = i / DM, n = i - (i / DM) * DM;
    WoT[(size_t)n * INNER + k] = (_Float16)WO[i];  // [DM][INNER] = WO^T
  }
}

// ---------------- prep: shift-replicated bias table biasS[h][c][4104] ----------------
__global__ void prep_bias(const float* __restrict__ rel_bias, float* __restrict__ biasS) {
  int idx = blockIdx.x * blockDim.x + threadIdx.x;
  const int TOT = NH * 4 * 4104;
  if (idx >= TOT) return;
  int h = idx / (4 * 4104);
  int rem = idx - h * 4 * 4104;
  int cc = rem / 4104;
  int i = rem - cc * 4104;
  int j = i + cc; if (j > 4094) j = 4094;
  int d = j - 2047;                 // relative position k - q
  int ret = d > 0 ? 16 : 0;
  int a = d < 0 ? -d : d;
  int bucket;
  if (a < 8) bucket = ret + a;
  else {
    int large;
    if      (a >= 91) large = 15;
    else if (a >= 64) large = 14;
    else if (a >= 46) large = 13;
    else if (a >= 32) large = 12;
    else if (a >= 23) large = 11;
    else if (a >= 16) large = 10;
    else if (a >= 12) large = 9;
    else              large = 8;
    bucket = ret + large;
  }
  biasS[idx] = rel_bias[bucket * NH + h] * LOG2E;
}

// ---------------- projection GEMM, m97-structure ----------------
__global__ __launch_bounds__(256) void proj_gemm(
    const float* __restrict__ Xq, const float* __restrict__ Xkv,
    const _Float16* __restrict__ WqT, const _Float16* __restrict__ WkvT,
    _Float16* __restrict__ Qo, _Float16* __restrict__ Ko, _Float16* __restrict__ Vto) {
  const int bm = blockIdx.x, by = blockIdx.y;
  const bool isQ = by < 3;
  const float* __restrict__ X = isQ ? Xq : Xkv;
  const _Float16* __restrict__ WT = isQ ? (WqT + (size_t)by * 128 * DM)
                                        : (WkvT + (size_t)(by - 3) * 128 * DM);

  __shared__ alignas(16) float    As[2][128 * 32];
  __shared__ alignas(16) _Float16 Bs[2][128 * 32];

  const int tid = threadIdx.x;
  const int lane = tid & 63, wave = tid >> 6;
  const int wm = wave >> 1, wn = wave & 1;
  const int l15 = lane & 15, lg = lane >> 4;

  f32x4 acc[4][4] = {};

  const int aoff = 4 * ((lane & 7) ^ (lane >> 3));
  const float* asrc[4];
#pragma unroll
  for (int c = 0; c < 4; ++c)
    asrc[c] = X + (size_t)(bm * 128 + (wave * 4 + c) * 8 + (lane >> 3)) * DM + aoff;
  const int boff = 8 * ((lane & 3) ^ ((lane >> 3) & 3));
  const _Float16* bsrc[2];
#pragma unroll
  for (int c = 0; c < 2; ++c)
    bsrc[c] = WT + (size_t)((wave * 2 + c) * 16 + (lane >> 2)) * DM + boff;

  const int NT = DM / 32;   // 46

#pragma unroll
  for (int c = 0; c < 4; ++c)
    gload16(asrc[c], (const char*)&As[0][0] + (wave * 4 + c) * 1024);
#pragma unroll
  for (int c = 0; c < 2; ++c)
    gload16(bsrc[c], (const char*)&Bs[0][0] + (wave * 2 + c) * 1024);
  __syncthreads();

  for (int t = 0; t < NT; ++t) {
    if (t + 1 < NT) {
      const int nb = (t + 1) & 1;
      const int kf = (t + 1) * 32;
#pragma unroll
      for (int c = 0; c < 4; ++c)
        gload16(asrc[c] + kf, (const char*)&As[nb][0] + (wave * 4 + c) * 1024);
#pragma unroll
      for (int c = 0; c < 2; ++c)
        gload16(bsrc[c] + kf, (const char*)&Bs[nb][0] + (wave * 2 + c) * 1024);
    }

    const char* Ab = (const char*)&As[t & 1][0];
    const char* Bb = (const char*)&Bs[t & 1][0];
    half8 af[4], bf[4];
#pragma unroll
    for (int m = 0; m < 4; ++m) {
      int r = wm * 64 + m * 16 + l15;
      int s = (r & 7) << 4;
      f32x4 x0 = *(const f32x4*)(Ab + r * 128 + ((lg * 32) ^ s));
      f32x4 x1 = *(const f32x4*)(Ab + r * 128 + ((lg * 32 + 16) ^ s));
      half8 h;
#pragma unroll
      for (int j = 0; j < 4; ++j) { h[j] = (_Float16)x0[j]; h[4 + j] = (_Float16)x1[j]; }
      af[m] = h;
    }
#pragma unroll
    for (int n = 0; n < 4; ++n) {
      int r = wn * 64 + n * 16 + l15;
      bf[n] = *(const half8*)(Bb + r * 64 + ((lg * 16) ^ (((r >> 1) & 3) << 4)));
    }

    __builtin_amdgcn_s_setprio(1);
#pragma unroll
    for (int m = 0; m < 4; ++m)
#pragma unroll
      for (int n = 0; n < 4; ++n)
        acc[m][n] = __builtin_amdgcn_mfma_f32_16x16x32_f16(af[m], bf[n], acc[m][n], 0, 0, 0);
    __builtin_amdgcn_s_setprio(0);

    __syncthreads();
  }

#pragma unroll
  for (int m = 0; m < 4; ++m)
#pragma unroll
    for (int n = 0; n < 4; ++n)
#pragma unroll
      for (int r = 0; r < 4; ++r) {
        int gm = bm * 128 + wm * 64 + m * 16 + lg * 4 + r;
        int gnl = wn * 64 + n * 16 + l15;
        int b = gm >> 11, s = gm & 2047;
        float av = acc[m][n][r];
        if (isQ) {
          int gn = by * 128 + gnl;
          int h = gn >> 6, dd = gn & 63;
          Qo[((size_t)(b * NH + h) * SEQ + s) * DKV + dd] = (_Float16)(av * LOG2E);
        } else {
          int gn = (by - 3) * 128 + gnl;
          if (gn < INNER) {
            int h = gn >> 6, dd = gn & 63;
            Ko[((size_t)(b * NH + h) * SEQ + s) * DKV + dd] = (_Float16)av;
          } else {
            int gnv = gn - INNER;
            int h = gnv >> 6, dd = gnv & 63;
            Vto[((size_t)(b * NH + h) * DKV + dd) * SEQ + s] = (_Float16)av;
          }
        }
      }
}

// ---------------- flash attention v4: round-4 skeleton + mask/bias pipeline +
// defer-max + lazy l-reduce ----------------
__global__ __launch_bounds__(256, 3) void attn_kernel(
    const _Float16* __restrict__ Q, const _Float16* __restrict__ K, const _Float16* __restrict__ Vt,
    const float* __restrict__ biasS, const float* __restrict__ mask, _Float16* __restrict__ AO) {
  const int bid = blockIdx.x;
  const int g = (bid & 7) * 96 + (bid >> 3);
  const int bh = g >> 5, qb = g & 31;
  const int b = bh / NH, h = bh - b * NH;
  const int q0 = qb * 64;
  const int tid = threadIdx.x, lane = tid & 63, wave = tid >> 6;
  const int l15 = lane & 15, lg = lane >> 4;

  __shared__ alignas(16) _Float16 Ks[2][64 * 64];
  __shared__ alignas(16) _Float16 Vs[2][64 * 64];
  __shared__ alignas(16) _Float16 Ps[4][16 * 72];   // 144B rows (pad) per wave

  const size_t bhS = (size_t)bh * SEQ;
  const int qq = q0 + wave * 16 + l15;

  const _Float16* Qbase = Q + (bhS + q0 + wave * 16) * DKV;
  half8 qf0 = *(const half8*)(Qbase + (size_t)l15 * DKV + lg * 8);
  half8 qf1 = *(const half8*)(Qbase + (size_t)l15 * DKV + 32 + lg * 8);

  const float* maskrow = mask + (size_t)b * SEQ * SEQ + (size_t)qq * SEQ + lg * 4;
  const int c = (3 - l15) & 3;
  const float* bbase = biasS + (size_t)(h * 4 + c) * 4104 + (lg * 4 - qq + 2047 - c);

  float m_r = -1e30f, l_acc = 0.f;
  f32x4 oacc[4] = {};

  const int srow = tid >> 2;
  const int scb = (tid & 3) * 32;
  const _Float16* Ksrc = K + (bhS + srow) * DKV + (scb >> 1);
  const _Float16* Vsrc = Vt + ((size_t)bh * DKV + srow) * SEQ + (scb >> 1);

  // prologue: stage K/V tile 0
  {
    half8 k0v = *(const half8*)(Ksrc);
    half8 k1v = *(const half8*)(Ksrc + 8);
    half8 v0v = *(const half8*)(Vsrc);
    half8 v1v = *(const half8*)(Vsrc + 8);
    char* KsW = (char*)&Ks[0][0];
    char* VsW = (char*)&Vs[0][0];
    *(half8*)(KsW + srow * 128 + swz128(srow, scb)) = k0v;
    *(half8*)(KsW + srow * 128 + swz128(srow, scb + 16)) = k1v;
    *(half8*)(VsW + srow * 128 + swz128(srow, scb)) = v0v;
    *(half8*)(VsW + srow * 128 + swz128(srow, scb + 16)) = v1v;
  }

  // prologue: mask/bias for tile 0 (pipelined one tile ahead thereafter)
  f32x4 mc[4], bc[4];
#pragma unroll
  for (int nf = 0; nf < 4; ++nf) {
    mc[nf] = *(const f32x4*)(maskrow + nf * 16);
    bc[nf] = *(const f32x4*)(bbase + nf * 16);
  }

#pragma unroll 2
  for (int t = 0; t < SEQ / 64; ++t) {
    __syncthreads();
    const int kt = t * 64;
    const bool pre = (t + 1 < SEQ / 64);
    half8 knA, knB, vnA, vnB;
    f32x4 mn[4], bn[4];
    if (pre) {
      const _Float16* kp = Ksrc + (size_t)(kt + 64) * DKV;
      knA = *(const half8*)(kp);
      knB = *(const half8*)(kp + 8);
      const _Float16* vp = Vsrc + kt + 64;
      vnA = *(const half8*)(vp);
      vnB = *(const half8*)(vp + 8);
#pragma unroll
      for (int nf = 0; nf < 4; ++nf) {
        mn[nf] = *(const f32x4*)(maskrow + kt + 64 + nf * 16);
        bn[nf] = *(const f32x4*)(bbase + kt + 64 + nf * 16);
      }
    }
    const char* KsB = (const char*)&Ks[t & 1][0];
    const char* VsB = (const char*)&Vs[t & 1][0];
    char* PsB = (char*)&Ps[wave][0];

    // S^T = K Q^T : rows k, cols q
    f32x4 sacc[4] = {};
    __builtin_amdgcn_s_setprio(1);
#pragma unroll
    for (int nf = 0; nf < 4; ++nf) {
      int kr = nf * 16 + l15;
      half8 kf0 = *(const half8*)(KsB + kr * 128 + swz128(kr, lg * 16));
      half8 kf1 = *(const half8*)(KsB + kr * 128 + swz128(kr, 64 + lg * 16));
      sacc[nf] = __builtin_amdgcn_mfma_f32_16x16x32_f16(kf0, qf0, sacc[nf], 0, 0, 0);
      sacc[nf] = __builtin_amdgcn_mfma_f32_16x16x32_f16(kf1, qf1, sacc[nf], 0, 0, 0);
    }
    __builtin_amdgcn_s_setprio(0);

    // logits (bias prescaled by log2e; mask pipelined): tree max
    float sv[4][4];
    float fm[4];
#pragma unroll
    for (int nf = 0; nf < 4; ++nf) {
#pragma unroll
      for (int r = 0; r < 4; ++r)
        sv[nf][r] = sacc[nf][r] + bc[nf][r] + mc[nf][r] * LOG2E;
      fm[nf] = fmaxf(fmaxf(sv[nf][0], sv[nf][1]), fmaxf(sv[nf][2], sv[nf][3]));
    }
    float mx = fmaxf(fmaxf(fm[0], fm[1]), fmaxf(fm[2], fm[3]));
    mx = fmaxf(mx, __shfl_xor(mx, 16));
    mx = fmaxf(mx, __shfl_xor(mx, 32));

    // defer-max: rescale only when running max grows past THR=8 (base-2 domain)
    if (!__all(mx <= m_r + 8.0f)) {
      float mnew = fmaxf(m_r, mx);
      float sc_ = __builtin_amdgcn_exp2f(m_r - mnew);
      m_r = mnew;
      l_acc *= sc_;
      f32x4 scv;
#pragma unroll
      for (int r = 0; r < 4; ++r) scv[r] = __shfl(sc_, lg * 4 + r);
#pragma unroll
      for (int df = 0; df < 4; ++df) oacc[df] *= scv;
    }

    float rs = 0.f;
#pragma unroll
    for (int nf = 0; nf < 4; ++nf) {
      half4 ph;
#pragma unroll
      for (int r = 0; r < 4; ++r) {
        float p = __builtin_amdgcn_exp2f(sv[nf][r] - m_r);
        rs += p;
        ph[r] = (_Float16)p;
      }
      *(half4*)(PsB + l15 * 144 + nf * 32 + lg * 8) = ph;
    }
    l_acc += rs;   // per-lane partial; cross-lane reduce deferred to epilogue

    // O += P V
    __builtin_amdgcn_s_setprio(1);
#pragma unroll
    for (int ks = 0; ks < 2; ++ks) {
      half8 pa = *(const half8*)(PsB + l15 * 144 + ks * 64 + lg * 16);
#pragma unroll
      for (int df = 0; df < 4; ++df) {
        int vr = df * 16 + l15;
        half8 vb = *(const half8*)(VsB + vr * 128 + swz128(vr, ks * 64 + lg * 16));
        oacc[df] = __builtin_amdgcn_mfma_f32_16x16x32_f16(pa, vb, oacc[df], 0, 0, 0);
      }
    }
    __builtin_amdgcn_s_setprio(0);

    if (pre) {
      char* KsW = (char*)&Ks[(t + 1) & 1][0];
      char* VsW = (char*)&Vs[(t + 1) & 1][0];
      *(half8*)(KsW + srow * 128 + swz128(srow, scb)) = knA;
      *(half8*)(KsW + srow * 128 + swz128(srow, scb + 16)) = knB;
      *(half8*)(VsW + srow * 128 + swz128(srow, scb)) = vnA;
      *(half8*)(VsW + srow * 128 + swz128(srow, scb + 16)) = vnB;
      // rotate pipelined mask/bias (moves vanish under unroll-2 renaming)
#pragma unroll
      for (int nf = 0; nf < 4; ++nf) { mc[nf] = mn[nf]; bc[nf] = bn[nf]; }
    }
  }

  // epilogue: finish l reduction, broadcast to o-row layout, normalize, store
  l_acc += __shfl_xor(l_acc, 16);
  l_acc += __shfl_xor(l_acc, 32);
  f32x4 lv;
#pragma unroll
  for (int r = 0; r < 4; ++r) lv[r] = __shfl(l_acc, lg * 4 + r);
#pragma unroll
  for (int df = 0; df < 4; ++df) {
    int dd = df * 16 + l15;
#pragma unroll
    for (int r = 0; r < 4; ++r) {
      int qrow = q0 + wave * 16 + lg * 4 + r;
      AO[((size_t)(b * SEQ + qrow)) * INNER + h * DKV + dd] = (_Float16)(oacc[df][r] / lv[r]);
    }
  }
}

// ---------------- output GEMM: AO[8192,384]f16 @ WO -> out fp32, double-buffered ----------------
__global__ __launch_bounds__(256) void out_gemm(
    const _Float16* __restrict__ A, const _Float16* __restrict__ BT, float* __restrict__ C) {
  __shared__ alignas(16) _Float16 As[2][128 * 32];
  __shared__ alignas(16) _Float16 Bs[2][64 * 32];

  const int tid = threadIdx.x, lane = tid & 63, wave = tid >> 6;
  const int wm = wave >> 1, wn = wave & 1;
  const int bm = blockIdx.x, bn = blockIdx.y;
  const int l15 = lane & 15, lg = lane >> 4;

  f32x4 acc[4][2] = {};
  const int arow = tid >> 1, aseg = tid & 1;
  const int brow = tid >> 2, bchunk = tid & 3;
  const _Float16* asrc = A + (size_t)(bm * 128 + arow) * INNER + aseg * 16;
  const _Float16* bsrc = BT + (size_t)(bn * 64 + brow) * INNER + bchunk * 8;

  const int NT = INNER / 32;  // 12

  {
    half8 a0 = *(const half8*)(asrc);
    half8 a1 = *(const half8*)(asrc + 8);
    half8 b0 = *(const half8*)(bsrc);
    char* AsW = (char*)&As[0][0];
    char* BsW = (char*)&Bs[0][0];
    *(half8*)(AsW + arow * 64 + swz64(arow, aseg * 32)) = a0;
    *(half8*)(AsW + arow * 64 + swz64(arow, aseg * 32 + 16)) = a1;
    *(half8*)(BsW + brow * 64 + swz64(brow, bchunk * 16)) = b0;
  }

  for (int t = 0; t < NT; ++t) {
    __syncthreads();
    const bool pre = (t + 1 < NT);
    half8 na0, na1, nb0;
    if (pre) {
      const int kn = (t + 1) * 32;
      na0 = *(const half8*)(asrc + kn);
      na1 = *(const half8*)(asrc + kn + 8);
      nb0 = *(const half8*)(bsrc + kn);
    }

    const char* AsB = (const char*)&As[t & 1][0];
    const char* BsB = (const char*)&Bs[t & 1][0];
    half8 af[4], bf[2];
#pragma unroll
    for (int m = 0; m < 4; ++m) {
      int r = wm * 64 + m * 16 + l15;
      af[m] = *(const half8*)(AsB + r * 64 + swz64(r, lg * 16));
    }
#pragma unroll
    for (int n = 0; n < 2; ++n) {
      int r = wn * 32 + n * 16 + l15;
      bf[n] = *(const half8*)(BsB + r * 64 + swz64(r, lg * 16));
    }
    __builtin_amdgcn_s_setprio(1);
#pragma unroll
    for (int m = 0; m < 4; ++m)
#pragma unroll
      for (int n = 0; n < 2; ++n)
        acc[m][n] = __builtin_amdgcn_mfma_f32_16x16x32_f16(af[m], bf[n], acc[m][n], 0, 0, 0);
    __builtin_amdgcn_s_setprio(0);

    if (pre) {
      char* AsW = (char*)&As[(t + 1) & 1][0];
      char* BsW = (char*)&Bs[(t + 1) & 1][0];
      *(half8*)(AsW + arow * 64 + swz64(arow, aseg * 32)) = na0;
      *(half8*)(AsW + arow * 64 + swz64(arow, aseg * 32 + 16)) = na1;
      *(half8*)(BsW + brow * 64 + swz64(brow, bchunk * 16)) = nb0;
    }
  }

#pragma unroll
  for (int m = 0; m < 4; ++m)
#pragma unroll
    for (int n = 0; n < 2; ++n)
#pragma unroll
      for (int r = 0; r < 4; ++r) {
        int gm = bm * 128 + wm * 64 + m * 16 + lg * 4 + r;
        int gn = bn * 64 + wn * 32 + n * 16 + l15;
        C[(size_t)gm * DM + gn] = acc[m][n][r];
      }
}

// ---------------- launch ----------------
extern "C" void kernel_launch(void* const* d_in, const int* in_sizes, int n_in,
                              void* d_out, int out_size, void* d_ws, size_t ws_size,
                              hipStream_t stream) {
  const float* kv   = (const float*)d_in[0];
  const float* qs   = (const float*)d_in[1];
  const float* mask = (const float*)d_in[2];
  const float* WQ   = (const float*)d_in[3];
  const float* WK   = (const float*)d_in[4];
  const float* WV   = (const float*)d_in[5];
  const float* WO   = (const float*)d_in[6];
  const float* rb   = (const float*)d_in[7];
  float* out = (float*)d_out;
  char* ws = (char*)d_ws;

  const size_t WT_BYTES  = (size_t)INNER * DM * 2;
  const size_t QKV_BYTES = (size_t)BATCH * NH * SEQ * DKV * 2;
  _Float16* WqT = (_Float16*)(ws);
  _Float16* WkT = (_Float16*)(ws + WT_BYTES);      // WkT + WvT contiguous => [768][DM]
  _Float16* WvT = (_Float16*)(ws + 2 * WT_BYTES);
  _Float16* WoT = (_Float16*)(ws + 3 * WT_BYTES);
  _Float16* Qh  = (_Float16*)(ws + 4 * WT_BYTES);
  _Float16* Kh  = (_Float16*)(ws + 4 * WT_BYTES + QKV_BYTES);
  _Float16* Vth = (_Float16*)(ws + 4 * WT_BYTES + 2 * QKV_BYTES);
  _Float16* AO  = (_Float16*)(ws + 4 * WT_BYTES + 3 * QKV_BYTES);
  float* biasS  = (float*)(ws + 4 * WT_BYTES + 4 * QKV_BYTES);

  hipLaunchKernelGGL(prep_weights, dim3((4 * DM * INNER + 255) / 256), dim3(256), 0, stream,
                     WQ, WK, WV, WO, WqT, WkT, WvT, WoT);
  hipLaunchKernelGGL(prep_bias, dim3((NH * 4 * 4104 + 255) / 256), dim3(256), 0, stream, rb, biasS);
  hipLaunchKernelGGL(proj_gemm, dim3(64, 9), dim3(256), 0, stream,
                     qs, kv, WqT, WkT, Qh, Kh, Vth);
  hipLaunchKernelGGL(attn_kernel, dim3(768), dim3(256), 0, stream,
                     Qh, Kh, Vth, biasS, mask, AO);
  hipLaunchKernelGGL(out_gemm, dim3(64, 23), dim3(256), 0, stream, AO, WoT, out);
}

// Round 7
// 193.717 us; speedup vs baseline: 1.0927x; 1.0045x over previous
//
#include <hip/hip_runtime.h>
#include <hip/hip_fp16.h>
#include <cstdint>

#define DM    1472
#define NH    6
#define DKV   64
#define INNER 384
#define BATCH 4
#define SEQ   2048
#define LOG2E 1.4426950408889634f

typedef __attribute__((ext_vector_type(8))) _Float16 half8;
typedef __attribute__((ext_vector_type(4))) _Float16 half4;
typedef __attribute__((ext_vector_type(4))) float f32x4;

__device__ __forceinline__ int swz64(int row, int b)  { return b ^ (((row >> 1) & 3) << 4); }

__device__ __forceinline__ void gload16(const void* g, const void* l) {
  __builtin_amdgcn_global_load_lds((const __attribute__((address_space(1))) void*)g,
                                   (__attribute__((address_space(3))) void*)l, 16, 0, 0);
}

// ---------------- prep: weights fp32 -> fp16 transposed ----------------
__global__ void prep_weights(const float* __restrict__ WQ, const float* __restrict__ WK,
                             const float* __restrict__ WV, const float* __restrict__ WO,
                             _Float16* __restrict__ WqT, _Float16* __restrict__ WkT,
                             _Float16* __restrict__ WvT, _Float16* __restrict__ WoT) {
  int idx = blockIdx.x * blockDim.x + threadIdx.x;
  const int per = DM * INNER;
  if (idx >= 4 * per) return;
  int which = idx / per;
  int i = idx - which * per;
  if (which < 3) {
    const float* W = which == 0 ? WQ : (which == 1 ? WK : WV);
    _Float16* T = which == 0 ? WqT : (which == 1 ? WkT : WvT);
    int k = i / INNER, n = i - (i / INNER) * INNER;
    T[(size_t)n * DM + k] = (_Float16)W[i];   // [INNER][DM] = W^T
  } else {
    int k = i / DM, n = i - (i / DM) * DM;
    WoT[(size_t)n * INNER + k] = (_Float16)WO[i];  // [DM][INNER] = WO^T
  }
}

// ---------------- prep: shift-replicated bias table biasS[h][c][4104] ----------------
__global__ void prep_bias(const float* __restrict__ rel_bias, float* __restrict__ biasS) {
  int idx = blockIdx.x * blockDim.x + threadIdx.x;
  const int TOT = NH * 4 * 4104;
  if (idx >= TOT) return;
  int h = idx / (4 * 4104);
  int rem = idx - h * 4 * 4104;
  int cc = rem / 4104;
  int i = rem - cc * 4104;
  int j = i + cc; if (j > 4094) j = 4094;
  int d = j - 2047;                 // relative position k - q
  int ret = d > 0 ? 16 : 0;
  int a = d < 0 ? -d : d;
  int bucket;
  if (a < 8) bucket = ret + a;
  else {
    int large;
    if      (a >= 91) large = 15;
    else if (a >= 64) large = 14;
    else if (a >= 46) large = 13;
    else if (a >= 32) large = 12;
    else if (a >= 23) large = 11;
    else if (a >= 16) large = 10;
    else if (a >= 12) large = 9;
    else              large = 8;
    bucket = ret + large;
  }
  biasS[idx] = rel_bias[bucket * NH + h] * LOG2E;
}

// ---------------- projection GEMM, m97-structure (unchanged, validated) ----------------
__global__ __launch_bounds__(256) void proj_gemm(
    const float* __restrict__ Xq, const float* __restrict__ Xkv,
    const _Float16* __restrict__ WqT, const _Float16* __restrict__ WkvT,
    _Float16* __restrict__ Qo, _Float16* __restrict__ Ko, _Float16* __restrict__ Vto) {
  const int bm = blockIdx.x, by = blockIdx.y;
  const bool isQ = by < 3;
  const float* __restrict__ X = isQ ? Xq : Xkv;
  const _Float16* __restrict__ WT = isQ ? (WqT + (size_t)by * 128 * DM)
                                        : (WkvT + (size_t)(by - 3) * 128 * DM);

  __shared__ alignas(16) float    As[2][128 * 32];
  __shared__ alignas(16) _Float16 Bs[2][128 * 32];

  const int tid = threadIdx.x;
  const int lane = tid & 63, wave = tid >> 6;
  const int wm = wave >> 1, wn = wave & 1;
  const int l15 = lane & 15, lg = lane >> 4;

  f32x4 acc[4][4] = {};

  const int aoff = 4 * ((lane & 7) ^ (lane >> 3));
  const float* asrc[4];
#pragma unroll
  for (int c = 0; c < 4; ++c)
    asrc[c] = X + (size_t)(bm * 128 + (wave * 4 + c) * 8 + (lane >> 3)) * DM + aoff;
  const int boff = 8 * ((lane & 3) ^ ((lane >> 3) & 3));
  const _Float16* bsrc[2];
#pragma unroll
  for (int c = 0; c < 2; ++c)
    bsrc[c] = WT + (size_t)((wave * 2 + c) * 16 + (lane >> 2)) * DM + boff;

  const int NT = DM / 32;   // 46

#pragma unroll
  for (int c = 0; c < 4; ++c)
    gload16(asrc[c], (const char*)&As[0][0] + (wave * 4 + c) * 1024);
#pragma unroll
  for (int c = 0; c < 2; ++c)
    gload16(bsrc[c], (const char*)&Bs[0][0] + (wave * 2 + c) * 1024);
  __syncthreads();

  for (int t = 0; t < NT; ++t) {
    if (t + 1 < NT) {
      const int nb = (t + 1) & 1;
      const int kf = (t + 1) * 32;
#pragma unroll
      for (int c = 0; c < 4; ++c)
        gload16(asrc[c] + kf, (const char*)&As[nb][0] + (wave * 4 + c) * 1024);
#pragma unroll
      for (int c = 0; c < 2; ++c)
        gload16(bsrc[c] + kf, (const char*)&Bs[nb][0] + (wave * 2 + c) * 1024);
    }

    const char* Ab = (const char*)&As[t & 1][0];
    const char* Bb = (const char*)&Bs[t & 1][0];
    half8 af[4], bf[4];
#pragma unroll
    for (int m = 0; m < 4; ++m) {
      int r = wm * 64 + m * 16 + l15;
      int s = (r & 7) << 4;
      f32x4 x0 = *(const f32x4*)(Ab + r * 128 + ((lg * 32) ^ s));
      f32x4 x1 = *(const f32x4*)(Ab + r * 128 + ((lg * 32 + 16) ^ s));
      half8 h;
#pragma unroll
      for (int j = 0; j < 4; ++j) { h[j] = (_Float16)x0[j]; h[4 + j] = (_Float16)x1[j]; }
      af[m] = h;
    }
#pragma unroll
    for (int n = 0; n < 4; ++n) {
      int r = wn * 64 + n * 16 + l15;
      bf[n] = *(const half8*)(Bb + r * 64 + ((lg * 16) ^ (((r >> 1) & 3) << 4)));
    }

    __builtin_amdgcn_s_setprio(1);
#pragma unroll
    for (int m = 0; m < 4; ++m)
#pragma unroll
      for (int n = 0; n < 4; ++n)
        acc[m][n] = __builtin_amdgcn_mfma_f32_16x16x32_f16(af[m], bf[n], acc[m][n], 0, 0, 0);
    __builtin_amdgcn_s_setprio(0);

    __syncthreads();
  }

#pragma unroll
  for (int m = 0; m < 4; ++m)
#pragma unroll
    for (int n = 0; n < 4; ++n)
#pragma unroll
      for (int r = 0; r < 4; ++r) {
        int gm = bm * 128 + wm * 64 + m * 16 + lg * 4 + r;
        int gnl = wn * 64 + n * 16 + l15;
        int b = gm >> 11, s = gm & 2047;
        float av = acc[m][n][r];
        if (isQ) {
          int gn = by * 128 + gnl;
          int h = gn >> 6, dd = gn & 63;
          Qo[((size_t)(b * NH + h) * SEQ + s) * DKV + dd] = (_Float16)(av * LOG2E);
        } else {
          int gn = (by - 3) * 128 + gnl;
          if (gn < INNER) {
            int h = gn >> 6, dd = gn & 63;
            Ko[((size_t)(b * NH + h) * SEQ + s) * DKV + dd] = (_Float16)av;
          } else {
            int gnv = gn - INNER;
            int h = gnv >> 6, dd = gnv & 63;
            Vto[((size_t)(b * NH + h) * DKV + dd) * SEQ + s] = (_Float16)av;
          }
        }
      }
}

// ---------------- flash attention v5: gload_lds staging, K 3-buf, QK^T(t+1) || softmax(t) ----------------
__global__ __launch_bounds__(256, 3) void attn_kernel(
    const _Float16* __restrict__ Q, const _Float16* __restrict__ K, const _Float16* __restrict__ Vt,
    const float* __restrict__ biasS, const float* __restrict__ mask, _Float16* __restrict__ AO) {
  const int bid = blockIdx.x;
  const int g = (bid & 7) * 96 + (bid >> 3);
  const int bh = g >> 5, qb = g & 31;
  const int b = bh / NH, h = bh - b * NH;
  const int q0 = qb * 64;
  const int tid = threadIdx.x, lane = tid & 63, wave = tid >> 6;
  const int l15 = lane & 15, lg = lane >> 4;
  const int NT = SEQ / 64;  // 32

  __shared__ alignas(16) _Float16 Ks[3][64 * 64];   // 24 KB, k-rows, 128B rows
  __shared__ alignas(16) _Float16 Vs[2][64 * 64];   // 16 KB, d-rows, 128B rows
  __shared__ alignas(16) _Float16 Ps[4][16 * 72];   //  9 KB, per-wave, 144B rows

  const size_t bhS = (size_t)bh * SEQ;
  const int qq = q0 + wave * 16 + l15;

  const _Float16* Qbase = Q + (bhS + q0 + wave * 16) * DKV;
  half8 qf0 = *(const half8*)(Qbase + (size_t)l15 * DKV + lg * 8);
  half8 qf1 = *(const half8*)(Qbase + (size_t)l15 * DKV + 32 + lg * 8);

  const float* maskrow = mask + (size_t)b * SEQ * SEQ + (size_t)qq * SEQ + lg * 4;
  const int c = (3 - l15) & 3;
  const float* bbase = biasS + (size_t)(h * 4 + c) * 4104 + (lg * 4 - qq + 2047 - c);

  float m_r = -1e30f, l_acc = 0.f;
  f32x4 oacc[4] = {};

  // ---- DMA staging geometry: pre-swizzled global source, linear LDS dest ----
  const int rl = lane >> 3;                         // row-in-8 (== row&7 of covered rows)
  const int sw = ((lane & 7) ^ rl) * 8;             // swizzled source chunk (f16 elems)
  const _Float16* Kd0 = K + (bhS + wave * 16 + rl) * DKV + sw;
  const _Float16* Kd1 = Kd0 + 8 * DKV;
  const _Float16* Vd0 = Vt + ((size_t)bh * DKV + wave * 16 + rl) * SEQ + sw;
  const _Float16* Vd1 = Vd0 + 8 * SEQ;
  char* KsB = (char*)&Ks[0][0];
  char* VsB = (char*)&Vs[0][0];
  char* PsB = (char*)&Ps[wave][0];
  const int dmaLds = wave * 2048;

  // prologue: DMA K0 (slot0), K1 (slot1), V0 (buf0)
  gload16(Kd0, KsB + dmaLds);
  gload16(Kd1, KsB + dmaLds + 1024);
  gload16(Kd0 + 64 * DKV, KsB + 8192 + dmaLds);
  gload16(Kd1 + 64 * DKV, KsB + 8192 + dmaLds + 1024);
  gload16(Vd0, VsB + dmaLds);
  gload16(Vd1, VsB + dmaLds + 1024);

  f32x4 mA[4], mB[4];
#pragma unroll
  for (int nf = 0; nf < 4; ++nf) mA[nf] = *(const f32x4*)(maskrow + nf * 16);

  __syncthreads();   // drains all prologue DMAs

  f32x4 sA[4] = {}, sB[4] = {};
  // QK^T(0) from slot 0
  __builtin_amdgcn_s_setprio(1);
#pragma unroll
  for (int nf = 0; nf < 4; ++nf) {
    int kr = nf * 16 + l15;
    const char* rb = KsB + kr * 128;
    half8 kf0 = *(const half8*)(rb + ((lg ^ (kr & 7)) << 4));
    half8 kf1 = *(const half8*)(rb + (((4 + lg) ^ (kr & 7)) << 4));
    sA[nf] = __builtin_amdgcn_mfma_f32_16x16x32_f16(kf0, qf0, sA[nf], 0, 0, 0);
    sA[nf] = __builtin_amdgcn_mfma_f32_16x16x32_f16(kf1, qf1, sA[nf], 0, 0, 0);
  }
  __builtin_amdgcn_s_setprio(0);

  auto body = [&](int t, f32x4 (&sC)[4], f32x4 (&sN)[4], f32x4 (&mC)[4], f32x4 (&mN)[4]) {
    const int nt1 = t + 1, nt2 = t + 2;
    // DMA K(t+2) -> slot (t+2)%3, V(t+1) -> buf (t+1)&1
    if (nt2 < NT) {
      char* kb = KsB + (nt2 % 3) * 8192 + dmaLds;
      gload16(Kd0 + (size_t)nt2 * 64 * DKV, kb);
      gload16(Kd1 + (size_t)nt2 * 64 * DKV, kb + 1024);
    }
    if (nt1 < NT) {
      char* vb_ = VsB + (nt1 & 1) * 8192 + dmaLds;
      gload16(Vd0 + nt1 * 64, vb_);
      gload16(Vd1 + nt1 * 64, vb_ + 1024);
      // mask for t+1 (register-pipelined)
#pragma unroll
      for (int nf = 0; nf < 4; ++nf)
        mN[nf] = *(const f32x4*)(maskrow + nt1 * 64 + nf * 16);
    }

    // QK^T(t+1) from slot (t+1)%3 — overlaps softmax(t) on the VALU pipe
#pragma unroll
    for (int nf = 0; nf < 4; ++nf) sN[nf] = (f32x4){0.f, 0.f, 0.f, 0.f};
    if (nt1 < NT) {
      const char* Kb = KsB + (nt1 % 3) * 8192;
      __builtin_amdgcn_s_setprio(1);
#pragma unroll
      for (int nf = 0; nf < 4; ++nf) {
        int kr = nf * 16 + l15;
        const char* rb = Kb + kr * 128;
        half8 kf0 = *(const half8*)(rb + ((lg ^ (kr & 7)) << 4));
        half8 kf1 = *(const half8*)(rb + (((4 + lg) ^ (kr & 7)) << 4));
        sN[nf] = __builtin_amdgcn_mfma_f32_16x16x32_f16(kf0, qf0, sN[nf], 0, 0, 0);
        sN[nf] = __builtin_amdgcn_mfma_f32_16x16x32_f16(kf1, qf1, sN[nf], 0, 0, 0);
      }
      __builtin_amdgcn_s_setprio(0);
    }

    // softmax(t): logits in place (bias from L2 at use; mask pipelined)
    float fm[4];
#pragma unroll
    for (int nf = 0; nf < 4; ++nf) {
      f32x4 bv = *(const f32x4*)(bbase + t * 64 + nf * 16);
#pragma unroll
      for (int r = 0; r < 4; ++r)
        sC[nf][r] = sC[nf][r] + bv[r] + mC[nf][r] * LOG2E;
      fm[nf] = fmaxf(fmaxf(sC[nf][0], sC[nf][1]), fmaxf(sC[nf][2], sC[nf][3]));
    }
    float mx = fmaxf(fmaxf(fm[0], fm[1]), fmaxf(fm[2], fm[3]));
    mx = fmaxf(mx, __shfl_xor(mx, 16));
    mx = fmaxf(mx, __shfl_xor(mx, 32));

    if (!__all(mx <= m_r + 8.0f)) {   // defer-max (T13)
      float mnew = fmaxf(m_r, mx);
      float sc_ = __builtin_amdgcn_exp2f(m_r - mnew);
      m_r = mnew;
      l_acc *= sc_;
      f32x4 scv;
#pragma unroll
      for (int r = 0; r < 4; ++r) scv[r] = __shfl(sc_, lg * 4 + r);
#pragma unroll
      for (int df = 0; df < 4; ++df) oacc[df] *= scv;
    }

    float rs = 0.f;
#pragma unroll
    for (int nf = 0; nf < 4; ++nf) {
      half4 ph;
#pragma unroll
      for (int r = 0; r < 4; ++r) {
        float p = __builtin_amdgcn_exp2f(sC[nf][r] - m_r);
        rs += p;
        ph[r] = (_Float16)p;
      }
      *(half4*)(PsB + l15 * 144 + nf * 32 + lg * 8) = ph;
    }
    l_acc += rs;

    // PV(t) from Vs[t&1]
    const char* Vb = VsB + (t & 1) * 8192;
    __builtin_amdgcn_s_setprio(1);
#pragma unroll
    for (int ks = 0; ks < 2; ++ks) {
      half8 pa = *(const half8*)(PsB + l15 * 144 + ks * 64 + lg * 16);
#pragma unroll
      for (int df = 0; df < 4; ++df) {
        int vr = df * 16 + l15;
        half8 vv = *(const half8*)(Vb + vr * 128 + (((ks * 4 + lg) ^ (vr & 7)) << 4));
        oacc[df] = __builtin_amdgcn_mfma_f32_16x16x32_f16(pa, vv, oacc[df], 0, 0, 0);
      }
    }
    __builtin_amdgcn_s_setprio(0);

    __syncthreads();   // one barrier/tile: drains this body's DMAs, fences LDS reuse
  };

  for (int tt = 0; tt < NT / 2; ++tt) {
    body(2 * tt,     sA, sB, mA, mB);
    body(2 * tt + 1, sB, sA, mB, mA);
  }

  // epilogue
  l_acc += __shfl_xor(l_acc, 16);
  l_acc += __shfl_xor(l_acc, 32);
  f32x4 lv;
#pragma unroll
  for (int r = 0; r < 4; ++r) lv[r] = __shfl(l_acc, lg * 4 + r);
#pragma unroll
  for (int df = 0; df < 4; ++df) {
    int dd = df * 16 + l15;
#pragma unroll
    for (int r = 0; r < 4; ++r) {
      int qrow = q0 + wave * 16 + lg * 4 + r;
      AO[((size_t)(b * SEQ + qrow)) * INNER + h * DKV + dd] = (_Float16)(oacc[df][r] / lv[r]);
    }
  }
}

// ---------------- output GEMM, m97-structure: gload_lds + dbuf ----------------
__global__ __launch_bounds__(256) void out_gemm(
    const _Float16* __restrict__ A, const _Float16* __restrict__ BT, float* __restrict__ C) {
  __shared__ alignas(16) _Float16 As[2][128 * 32];   // 8 KB/buf
  __shared__ alignas(16) _Float16 Bs[2][64 * 32];    // 4 KB/buf

  const int tid = threadIdx.x, lane = tid & 63, wave = tid >> 6;
  const int wm = wave >> 1, wn = wave & 1;
  const int bm = blockIdx.x, bn = blockIdx.y;
  const int l15 = lane & 15, lg = lane >> 4;

  f32x4 acc[4][2] = {};

  // DMA geometry: rows of 64B (4 chunks of 16B), swizzle chunk ^= row&3
  const int rl4 = (lane >> 2) & 3;                  // row&3 of covered rows
  const int soff = ((lane & 3) ^ rl4) * 8;          // source chunk offset (f16)
  const _Float16* ad0 = A + (size_t)(bm * 128 + (wave * 2) * 16 + (lane >> 2)) * INNER + soff;
  const _Float16* ad1 = ad0 + (size_t)16 * INNER;
  const _Float16* bd0 = BT + (size_t)(bn * 64 + wave * 16 + (lane >> 2)) * INNER + soff;
  char* AsB = (char*)&As[0][0];
  char* BsB = (char*)&Bs[0][0];
  const int aLds = wave * 2048;
  const int bLds = wave * 1024;

  const int NT = INNER / 32;  // 12

  gload16(ad0, AsB + aLds);
  gload16(ad1, AsB + aLds + 1024);
  gload16(bd0, BsB + bLds);
  __syncthreads();

  for (int t = 0; t < NT; ++t) {
    if (t + 1 < NT) {
      const int nb = (t + 1) & 1;
      const int kf = (t + 1) * 32;
      gload16(ad0 + kf, AsB + nb * 8192 + aLds);
      gload16(ad1 + kf, AsB + nb * 8192 + aLds + 1024);
      gload16(bd0 + kf, BsB + nb * 4096 + bLds);
    }

    const char* Ab = AsB + (t & 1) * 8192;
    const char* Bb = BsB + (t & 1) * 4096;
    half8 af[4], bf[2];
#pragma unroll
    for (int m = 0; m < 4; ++m) {
      int r = wm * 64 + m * 16 + l15;
      af[m] = *(const half8*)(Ab + r * 64 + (((lg ^ (r & 3))) << 4));
    }
#pragma unroll
    for (int n = 0; n < 2; ++n) {
      int r = wn * 32 + n * 16 + l15;
      bf[n] = *(const half8*)(Bb + r * 64 + (((lg ^ (r & 3))) << 4));
    }
    __builtin_amdgcn_s_setprio(1);
#pragma unroll
    for (int m = 0; m < 4; ++m)
#pragma unroll
      for (int n = 0; n < 2; ++n)
        acc[m][n] = __builtin_amdgcn_mfma_f32_16x16x32_f16(af[m], bf[n], acc[m][n], 0, 0, 0);
    __builtin_amdgcn_s_setprio(0);

    __syncthreads();
  }

#pragma unroll
  for (int m = 0; m < 4; ++m)
#pragma unroll
    for (int n = 0; n < 2; ++n)
#pragma unroll
      for (int r = 0; r < 4; ++r) {
        int gm = bm * 128 + wm * 64 + m * 16 + lg * 4 + r;
        int gn = bn * 64 + wn * 32 + n * 16 + l15;
        C[(size_t)gm * DM + gn] = acc[m][n][r];
      }
}

// ---------------- launch ----------------
extern "C" void kernel_launch(void* const* d_in, const int* in_sizes, int n_in,
                              void* d_out, int out_size, void* d_ws, size_t ws_size,
                              hipStream_t stream) {
  const float* kv   = (const float*)d_in[0];
  const float* qs   = (const float*)d_in[1];
  const float* mask = (const float*)d_in[2];
  const float* WQ   = (const float*)d_in[3];
  const float* WK   = (const float*)d_in[4];
  const float* WV   = (const float*)d_in[5];
  const float* WO   = (const float*)d_in[6];
  const float* rb   = (const float*)d_in[7];
  float* out = (float*)d_out;
  char* ws = (char*)d_ws;

  const size_t WT_BYTES  = (size_t)INNER * DM * 2;
  const size_t QKV_BYTES = (size_t)BATCH * NH * SEQ * DKV * 2;
  _Float16* WqT = (_Float16*)(ws);
  _Float16* WkT = (_Float16*)(ws + WT_BYTES);      // WkT + WvT contiguous => [768][DM]
  _Float16* WvT = (_Float16*)(ws + 2 * WT_BYTES);
  _Float16* WoT = (_Float16*)(ws + 3 * WT_BYTES);
  _Float16* Qh  = (_Float16*)(ws + 4 * WT_BYTES);
  _Float16* Kh  = (_Float16*)(ws + 4 * WT_BYTES + QKV_BYTES);
  _Float16* Vth = (_Float16*)(ws + 4 * WT_BYTES + 2 * QKV_BYTES);
  _Float16* AO  = (_Float16*)(ws + 4 * WT_BYTES + 3 * QKV_BYTES);
  float* biasS  = (float*)(ws + 4 * WT_BYTES + 4 * QKV_BYTES);

  hipLaunchKernelGGL(prep_weights, dim3((4 * DM * INNER + 255) / 256), dim3(256), 0, stream,
                     WQ, WK, WV, WO, WqT, WkT, WvT, WoT);
  hipLaunchKernelGGL(prep_bias, dim3((NH * 4 * 4104 + 255) / 256), dim3(256), 0, stream, rb, biasS);
  hipLaunchKernelGGL(proj_gemm, dim3(64, 9), dim3(256), 0, stream,
                     qs, kv, WqT, WkT, Qh, Kh, Vth);
  hipLaunchKernelGGL(attn_kernel, dim3(768), dim3(256), 0, stream,
                     Qh, Kh, Vth, biasS, mask, AO);
  hipLaunchKernelGGL(out_gemm, dim3(64, 23), dim3(256), 0, stream, AO, WoT, out);
}